// Round 1
// baseline (511.126 us; speedup 1.0000x reference)
//
#include <hip/hip_runtime.h>
#include <hip/hip_bf16.h>
#include <stdint.h>
#include <stddef.h>

#define RNUM   3
#define NNODES 50000
#define ENUM   1000000
#define BATCH  2048
#define INP    256
#define HID    512
#define OUTC   256
#define BN_EPS 1e-5f

// ---------------- init kernels ----------------

__global__ void k_init_inv(int* __restrict__ inv) {
    int i = blockIdx.x * blockDim.x + threadIdx.x;
    if (i < NNODES) inv[i] = -1;
}

__global__ void k_scatter_inv(const int* __restrict__ bn, int* __restrict__ inv) {
    int i = blockIdx.x * blockDim.x + threadIdx.x;
    if (i < BATCH) inv[bn[i]] = i;
}

__global__ void k_init_rel(int* __restrict__ appear, float* __restrict__ deg,
                           float* __restrict__ musum, float* __restrict__ sqsum,
                           int* __restrict__ kcount) {
    int i = blockIdx.x * blockDim.x + threadIdx.x;
    if (i < BATCH) { appear[i] = 0; deg[i] = 0.0f; }
    if (i < HID)   { musum[i] = 0.0f; sqsum[i] = 0.0f; }
    if (i == 0)    { *kcount = 0; }
}

// ---------------- edge mask + compact ----------------

__global__ void k_mask(const int* __restrict__ src, const int* __restrict__ dst,
                       const int* __restrict__ inv, int* __restrict__ appear,
                       int2* __restrict__ edges, int* __restrict__ kcount) {
    int stride = gridDim.x * blockDim.x;
    for (int e = blockIdx.x * blockDim.x + threadIdx.x; e < ENUM; e += stride) {
        int ps = inv[src[e]];
        int pd = inv[dst[e]];
        if (ps >= 0 && pd >= 0) {
            int idx = atomicAdd(kcount, 1);
            edges[idx] = make_int2(ps, pd);
            appear[ps] = 1;   // benign race: everyone writes 1
            appear[pd] = 1;
        }
    }
}

// exclusive-rank scan over 2048 elements (rank = inclusive cumsum - 1)
__global__ __launch_bounds__(1024) void k_scan2048(const int* __restrict__ appear,
                                                   int* __restrict__ rankArr) {
    __shared__ int buf[2][BATCH];
    int t = threadIdx.x;
    buf[0][t]        = appear[t];
    buf[0][t + 1024] = appear[t + 1024];
    __syncthreads();
    int cur = 0;
    for (int off = 1; off < BATCH; off <<= 1) {
        int nxt = cur ^ 1;
        int i1 = t, i2 = t + 1024;
        buf[nxt][i1] = buf[cur][i1] + (i1 >= off ? buf[cur][i1 - off] : 0);
        buf[nxt][i2] = buf[cur][i2] + (i2 >= off ? buf[cur][i2 - off] : 0);
        __syncthreads();
        cur = nxt;
    }
    rankArr[t]        = buf[cur][t] - 1;
    rankArr[t + 1024] = buf[cur][t + 1024] - 1;
}

// convert (batch-pos, batch-pos) -> (rank, rank) in place; accumulate degree
__global__ void k_deg(int2* __restrict__ edges, const int* __restrict__ rankArr,
                      const int* __restrict__ kcount, float* __restrict__ deg) {
    int K = *kcount;
    int stride = gridDim.x * blockDim.x;
    for (int e = blockIdx.x * blockDim.x + threadIdx.x; e < K; e += stride) {
        int2 ed = edges[e];
        int s = rankArr[ed.x];
        int d = rankArr[ed.y];
        edges[e] = make_int2(s, d);
        atomicAdd(&deg[d], 1.0f);  // exact: small-int float adds
    }
}

__global__ void k_dinv(const float* __restrict__ deg, float* __restrict__ dinv) {
    int i = blockIdx.x * blockDim.x + threadIdx.x;
    if (i < BATCH) dinv[i] = rsqrtf(deg[i] + 1.0f);
}

// ---------------- GEMMs (fp32 tiled, 64x64x16, 256 thr, 4x4 micro) ----------------

#define BM 64
#define BN 64
#define BK 16

// xw = gather(features, bn) @ W1 ; hbase = dinv^2 * xw + b1
__global__ __launch_bounds__(256) void k_gemm1(
    const float* __restrict__ feat,  // features + r*N*INP
    const int*   __restrict__ bn,
    const float* __restrict__ W,     // [INP, HID]
    const float* __restrict__ b1,
    const float* __restrict__ dinv,
    float* __restrict__ xw,          // [BATCH, HID]
    float* __restrict__ hbase)       // [BATCH, HID]
{
    __shared__ float As[BK][BM + 4];
    __shared__ float Bs[BK][BN + 4];
    const int tid = threadIdx.x;
    const int tx = tid & 15, ty = tid >> 4;
    const int m0 = blockIdx.y * BM, n0 = blockIdx.x * BN;

    const int arow = tid >> 2, akq = tid & 3;          // A: 64 rows x 4 float4
    const int gr   = bn[m0 + arow];
    const float* aptr = feat + (size_t)gr * INP + akq * 4;
    const int brow = tid >> 4, bcq = tid & 15;         // B: 16 rows x 16 float4

    float acc[4][4] = {};
    for (int k0 = 0; k0 < INP; k0 += BK) {
        float4 av = *(const float4*)(aptr + k0);
        As[akq * 4 + 0][arow] = av.x;
        As[akq * 4 + 1][arow] = av.y;
        As[akq * 4 + 2][arow] = av.z;
        As[akq * 4 + 3][arow] = av.w;
        float4 bv = *(const float4*)(W + (size_t)(k0 + brow) * HID + n0 + bcq * 4);
        *(float4*)&Bs[brow][bcq * 4] = bv;
        __syncthreads();
#pragma unroll
        for (int kk = 0; kk < BK; ++kk) {
            float4 a4 = *(const float4*)&As[kk][ty * 4];
            float4 b4 = *(const float4*)&Bs[kk][tx * 4];
            float a[4] = {a4.x, a4.y, a4.z, a4.w};
            float b[4] = {b4.x, b4.y, b4.z, b4.w};
#pragma unroll
            for (int i = 0; i < 4; ++i)
#pragma unroll
                for (int j = 0; j < 4; ++j)
                    acc[i][j] = fmaf(a[i], b[j], acc[i][j]);
        }
        __syncthreads();
    }
#pragma unroll
    for (int i = 0; i < 4; ++i) {
        int row = m0 + ty * 4 + i;
        float di = dinv[row];
        float d2 = di * di;
#pragma unroll
        for (int j = 0; j < 4; ++j) {
            int col = n0 + tx * 4 + j;
            float c = acc[i][j];
            xw[(size_t)row * HID + col]    = c;
            hbase[(size_t)row * HID + col] = d2 * c + b1[col];
        }
    }
}

// yw = BN(h) @ W2 ; dout = dinv^2 * yw + b2   (BN affine fused into A-load)
__global__ __launch_bounds__(256) void k_gemm2(
    const float* __restrict__ h,      // [BATCH, HID]
    const float* __restrict__ rstdg,  // [HID]  (= rsqrt(var+eps)*gamma)
    const float* __restrict__ shiftc, // [HID]  (= beta - mu*rstdg)
    const float* __restrict__ W,      // [HID, OUTC]
    const float* __restrict__ b2,
    const float* __restrict__ dinv,
    float* __restrict__ yw,           // [BATCH, OUTC]
    float* __restrict__ dout)         // out + r*BATCH*OUTC
{
    __shared__ float As[BK][BM + 4];
    __shared__ float Bs[BK][BN + 4];
    const int tid = threadIdx.x;
    const int tx = tid & 15, ty = tid >> 4;
    const int m0 = blockIdx.y * BM, n0 = blockIdx.x * BN;

    const int arow = tid >> 2, akq = tid & 3;
    const float* aptr = h + (size_t)(m0 + arow) * HID + akq * 4;
    const int brow = tid >> 4, bcq = tid & 15;

    float acc[4][4] = {};
    for (int k0 = 0; k0 < HID; k0 += BK) {
        float4 av = *(const float4*)(aptr + k0);
        float4 gg = *(const float4*)(rstdg + k0 + akq * 4);
        float4 sh = *(const float4*)(shiftc + k0 + akq * 4);
        As[akq * 4 + 0][arow] = av.x * gg.x + sh.x;
        As[akq * 4 + 1][arow] = av.y * gg.y + sh.y;
        As[akq * 4 + 2][arow] = av.z * gg.z + sh.z;
        As[akq * 4 + 3][arow] = av.w * gg.w + sh.w;
        float4 bv = *(const float4*)(W + (size_t)(k0 + brow) * OUTC + n0 + bcq * 4);
        *(float4*)&Bs[brow][bcq * 4] = bv;
        __syncthreads();
#pragma unroll
        for (int kk = 0; kk < BK; ++kk) {
            float4 a4 = *(const float4*)&As[kk][ty * 4];
            float4 b4 = *(const float4*)&Bs[kk][tx * 4];
            float a[4] = {a4.x, a4.y, a4.z, a4.w};
            float b[4] = {b4.x, b4.y, b4.z, b4.w};
#pragma unroll
            for (int i = 0; i < 4; ++i)
#pragma unroll
                for (int j = 0; j < 4; ++j)
                    acc[i][j] = fmaf(a[i], b[j], acc[i][j]);
        }
        __syncthreads();
    }
#pragma unroll
    for (int i = 0; i < 4; ++i) {
        int row = m0 + ty * 4 + i;
        float di = dinv[row];
        float d2 = di * di;
#pragma unroll
        for (int j = 0; j < 4; ++j) {
            int col = n0 + tx * 4 + j;
            float c = acc[i][j];
            yw[(size_t)row * OUTC + col]   = c;
            dout[(size_t)row * OUTC + col] = d2 * c + b2[col];
        }
    }
}

// ---------------- edge aggregation (scatter-add) ----------------

__global__ void k_agg(const int2* __restrict__ edges, const int* __restrict__ kcount,
                      const float* __restrict__ dinv, const float* __restrict__ src_mat,
                      float* __restrict__ dst_mat, int ncol) {
    int K = *kcount;
    for (int e = blockIdx.x; e < K; e += gridDim.x) {
        int2 ed = edges[e];
        float w = dinv[ed.x] * dinv[ed.y];
        const float* srow = src_mat + (size_t)ed.x * ncol;
        float* drow = dst_mat + (size_t)ed.y * ncol;
        for (int c = threadIdx.x; c < ncol; c += blockDim.x) {
            atomicAdd(&drow[c], w * srow[c]);
        }
    }
}

// ---------------- batch norm stats ----------------

__global__ __launch_bounds__(256) void k_bnstats(const float* __restrict__ h,
                                                 float* __restrict__ musum,
                                                 float* __restrict__ sqsum) {
    // 64 blocks x 32 rows each; thread t owns cols t and t+256
    int c0 = threadIdx.x;
    int r0 = blockIdx.x * 32;
    float s1a = 0, s2a = 0, s1b = 0, s2b = 0;
    for (int rr = 0; rr < 32; ++rr) {
        const float* row = h + (size_t)(r0 + rr) * HID;
        float va = row[c0];
        float vb = row[c0 + 256];
        s1a += va; s2a += va * va;
        s1b += vb; s2b += vb * vb;
    }
    atomicAdd(&musum[c0], s1a);       atomicAdd(&sqsum[c0], s2a);
    atomicAdd(&musum[c0 + 256], s1b); atomicAdd(&sqsum[c0 + 256], s2b);
}

__global__ void k_bnfinal(const float* __restrict__ musum, const float* __restrict__ sqsum,
                          const float* __restrict__ gamma, const float* __restrict__ beta,
                          float* __restrict__ rstdg, float* __restrict__ shiftc) {
    int c = blockIdx.x * blockDim.x + threadIdx.x;
    if (c < HID) {
        float mu  = musum[c] * (1.0f / BATCH);
        float ex2 = sqsum[c] * (1.0f / BATCH);
        float var = ex2 - mu * mu;
        float g = rsqrtf(var + BN_EPS) * gamma[c];
        rstdg[c]  = g;
        shiftc[c] = beta[c] - mu * g;
    }
}

// ---------------- launch ----------------

extern "C" void kernel_launch(void* const* d_in, const int* in_sizes, int n_in,
                              void* d_out, int out_size, void* d_ws, size_t ws_size,
                              hipStream_t stream) {
    const float* features    = (const float*)d_in[0];
    const float* W1          = (const float*)d_in[1];
    const float* b1          = (const float*)d_in[2];
    const float* W2          = (const float*)d_in[3];
    const float* b2          = (const float*)d_in[4];
    const float* gamma       = (const float*)d_in[5];
    const float* beta        = (const float*)d_in[6];
    const int*   edge_index  = (const int*)d_in[7];
    const int*   batch_nodes = (const int*)d_in[8];
    float* out = (float*)d_out;

    // workspace carve-up (aligned to 256 B)
    char* p = (char*)d_ws;
    size_t cur = 0;
    auto alloc = [&](size_t bytes) {
        void* r = p + cur;
        cur = (cur + bytes + 255) & ~(size_t)255;
        return r;
    };
    int*   inv    = (int*)  alloc(NNODES * sizeof(int));
    int*   appear = (int*)  alloc(BATCH * sizeof(int));
    int*   rankA  = (int*)  alloc(BATCH * sizeof(int));
    int*   kcount = (int*)  alloc(sizeof(int));
    float* deg    = (float*)alloc(BATCH * sizeof(float));
    float* dinv   = (float*)alloc(BATCH * sizeof(float));
    float* musum  = (float*)alloc(HID * sizeof(float));
    float* sqsum  = (float*)alloc(HID * sizeof(float));
    float* rstdg  = (float*)alloc(HID * sizeof(float));
    float* shiftc = (float*)alloc(HID * sizeof(float));
    int2*  edges  = (int2*) alloc((size_t)ENUM * sizeof(int2));
    float* xw     = (float*)alloc((size_t)BATCH * HID * sizeof(float));
    float* hbase  = (float*)alloc((size_t)BATCH * HID * sizeof(float));
    float* yw     = (float*)alloc((size_t)BATCH * OUTC * sizeof(float));
    (void)ws_size; (void)in_sizes; (void)n_in; (void)out_size;

    k_init_inv<<<(NNODES + 255) / 256, 256, 0, stream>>>(inv);
    k_scatter_inv<<<BATCH / 256, 256, 0, stream>>>(batch_nodes, inv);

    for (int r = 0; r < RNUM; ++r) {
        const int* src = edge_index + (size_t)r * 2 * ENUM;
        const int* dst = src + ENUM;
        const float* feat_r = features + (size_t)r * NNODES * INP;
        float* out_r = out + (size_t)r * BATCH * OUTC;

        k_init_rel<<<BATCH / 256, 256, 0, stream>>>(appear, deg, musum, sqsum, kcount);
        k_mask<<<1024, 256, 0, stream>>>(src, dst, inv, appear, edges, kcount);
        k_scan2048<<<1, 1024, 0, stream>>>(appear, rankA);
        k_deg<<<256, 256, 0, stream>>>(edges, rankA, kcount, deg);
        k_dinv<<<BATCH / 256, 256, 0, stream>>>(deg, dinv);

        k_gemm1<<<dim3(HID / BN, BATCH / BM), 256, 0, stream>>>(
            feat_r, batch_nodes, W1, b1, dinv, xw, hbase);
        k_agg<<<512, 256, 0, stream>>>(edges, kcount, dinv, xw, hbase, HID);

        k_bnstats<<<64, 256, 0, stream>>>(hbase, musum, sqsum);
        k_bnfinal<<<2, 256, 0, stream>>>(musum, sqsum, gamma, beta, rstdg, shiftc);

        k_gemm2<<<dim3(OUTC / BN, BATCH / BM), 256, 0, stream>>>(
            hbase, rstdg, shiftc, W2, b2, dinv, yw, out_r);
        k_agg<<<512, 256, 0, stream>>>(edges, kcount, dinv, yw, out_r, OUTC);
    }
}

// Round 2
// 329.477 us; speedup vs baseline: 1.5513x; 1.5513x over previous
//
#include <hip/hip_runtime.h>
#include <hip/hip_bf16.h>
#include <stdint.h>
#include <stddef.h>

#define RNUM   3
#define NNODES 50000
#define ENUM   1000000
#define BATCH  2048
#define INP    256
#define HID    512
#define OUTC   256
#define BN_EPS 1e-5f

typedef __bf16 bf16x8 __attribute__((ext_vector_type(8)));
typedef float  f32x4  __attribute__((ext_vector_type(4)));

__device__ inline unsigned short f2bf(float f) {
    union { float f; unsigned u; } c; c.f = f;
    unsigned u = c.u;
    return (unsigned short)((u + 0x7fffu + ((u >> 16) & 1u)) >> 16);  // RNE
}

__device__ inline uint4 pack8(float4 a, float4 b) {
    uint4 r;
    r.x = (unsigned)f2bf(a.x) | ((unsigned)f2bf(a.y) << 16);
    r.y = (unsigned)f2bf(a.z) | ((unsigned)f2bf(a.w) << 16);
    r.z = (unsigned)f2bf(b.x) | ((unsigned)f2bf(b.y) << 16);
    r.w = (unsigned)f2bf(b.z) | ((unsigned)f2bf(b.w) << 16);
    return r;
}

// ---------------- weight transpose + bf16 convert (once per launch) ----------------
// W [K][N] fp32 -> WT [N][K] bf16.  z=0: W1 (256x512), z=1: W2 (512x256)
__global__ __launch_bounds__(256) void k_wt(const float* __restrict__ W1,
                                            const float* __restrict__ W2,
                                            unsigned short* __restrict__ W1T,
                                            unsigned short* __restrict__ W2T) {
    __shared__ float T[32][33];
    int z = blockIdx.z;
    const float* W = z ? W2 : W1;
    unsigned short* WT = z ? W2T : W1T;
    int K = z ? HID : INP;
    int N = z ? OUTC : HID;
    int kt = blockIdx.y, nt = blockIdx.x;
    if (kt * 32 >= K || nt * 32 >= N) return;
    int tx = threadIdx.x & 31, ty = threadIdx.x >> 5;
#pragma unroll
    for (int j = 0; j < 4; ++j)
        T[ty + j * 8][tx] = W[(size_t)(kt * 32 + ty + j * 8) * N + nt * 32 + tx];
    __syncthreads();
#pragma unroll
    for (int j = 0; j < 4; ++j)
        WT[(size_t)(nt * 32 + ty + j * 8) * K + kt * 32 + tx] = f2bf(T[tx][ty + j * 8]);
}

// ---------------- init ----------------
__global__ void k_init(int* __restrict__ inv, int* __restrict__ appear,
                       float* __restrict__ deg, float* __restrict__ musum,
                       float* __restrict__ sqsum, int* __restrict__ kcount) {
    int i = blockIdx.x * blockDim.x + threadIdx.x;
    if (i < NNODES) inv[i] = -1;
    if (i < RNUM * BATCH) { appear[i] = 0; deg[i] = 0.0f; }
    if (i < RNUM * HID)   { musum[i] = 0.0f; sqsum[i] = 0.0f; }
    if (i < RNUM)         kcount[i] = 0;
}

__global__ void k_scatter_inv(const int* __restrict__ bn, int* __restrict__ inv) {
    int i = blockIdx.x * blockDim.x + threadIdx.x;
    if (i < BATCH) inv[bn[i]] = i;
}

// ---------------- edge mask + compact (z = relation) ----------------
__global__ void k_mask(const int* __restrict__ edge_index, const int* __restrict__ inv,
                       int* __restrict__ appear, int2* __restrict__ edges,
                       int* __restrict__ kcount) {
    int z = blockIdx.z;
    const int* src = edge_index + (size_t)z * 2 * ENUM;
    const int* dst = src + ENUM;
    int2* ed = edges + (size_t)z * ENUM;
    int* app = appear + z * BATCH;
    int stride = gridDim.x * blockDim.x;
    for (int e4 = blockIdx.x * blockDim.x + threadIdx.x; e4 < ENUM / 4; e4 += stride) {
        int4 s4 = ((const int4*)src)[e4];
        int4 d4 = ((const int4*)dst)[e4];
        int ss[4] = {s4.x, s4.y, s4.z, s4.w};
        int dd[4] = {d4.x, d4.y, d4.z, d4.w};
#pragma unroll
        for (int i = 0; i < 4; ++i) {
            int ps = inv[ss[i]];
            int pd = inv[dd[i]];
            if (ps >= 0 && pd >= 0) {
                int idx = atomicAdd(kcount + z, 1);
                ed[idx] = make_int2(ps, pd);
                app[ps] = 1;
                app[pd] = 1;
            }
        }
    }
}

// rank = inclusive-cumsum - 1 over 2048 appear flags; blockIdx.x = relation
__global__ __launch_bounds__(1024) void k_scan2048(const int* __restrict__ appear,
                                                   int* __restrict__ rankArr) {
    __shared__ int buf[2][BATCH];
    int z = blockIdx.x;
    const int* ap = appear + z * BATCH;
    int* rk = rankArr + z * BATCH;
    int t = threadIdx.x;
    buf[0][t] = ap[t];
    buf[0][t + 1024] = ap[t + 1024];
    __syncthreads();
    int cur = 0;
    for (int off = 1; off < BATCH; off <<= 1) {
        int nxt = cur ^ 1;
        int i1 = t, i2 = t + 1024;
        buf[nxt][i1] = buf[cur][i1] + (i1 >= off ? buf[cur][i1 - off] : 0);
        buf[nxt][i2] = buf[cur][i2] + (i2 >= off ? buf[cur][i2 - off] : 0);
        __syncthreads();
        cur = nxt;
    }
    rk[t] = buf[cur][t] - 1;
    rk[t + 1024] = buf[cur][t + 1024] - 1;
}

// remap edges to ranks in-place; accumulate degree
__global__ void k_deg(int2* __restrict__ edges, const int* __restrict__ rankArr,
                      const int* __restrict__ kcount, float* __restrict__ deg) {
    int z = blockIdx.z;
    int K = kcount[z];
    int2* ed = edges + (size_t)z * ENUM;
    const int* rk = rankArr + z * BATCH;
    float* dg = deg + z * BATCH;
    int stride = gridDim.x * blockDim.x;
    for (int e = blockIdx.x * blockDim.x + threadIdx.x; e < K; e += stride) {
        int2 E = ed[e];
        int s = rk[E.x], d = rk[E.y];
        ed[e] = make_int2(s, d);
        atomicAdd(&dg[d], 1.0f);
    }
}

// ---------------- MFMA GEMMs: 64x64 tile, 4 waves, 2x2 of 16x16x32 ----------------

// xw = gather(feat, bn) @ W1 ; hbase = xw/(deg+1) + b1
__global__ __launch_bounds__(256) void k_gemm1(
    const float* __restrict__ features, const int* __restrict__ bn,
    const unsigned short* __restrict__ W1T, const float* __restrict__ b1,
    const float* __restrict__ deg, float* __restrict__ xw, float* __restrict__ hbase) {
    __shared__ __align__(16) unsigned short As[64][40];
    __shared__ __align__(16) unsigned short Bs[64][40];
    int z = blockIdx.z;
    const float* feat = features + (size_t)z * NNODES * INP;
    const float* dgz = deg + z * BATCH;
    float* xwz = xw + (size_t)z * BATCH * HID;
    float* hbz = hbase + (size_t)z * BATCH * HID;
    int m0 = blockIdx.y * 64, n0 = blockIdx.x * 64;
    int t = threadIdx.x;
    int ar = t >> 2, aq = t & 3;                       // staging: row, k-octet
    int grow = bn[m0 + ar];
    const float* aptr = feat + (size_t)grow * INP + aq * 8;
    const unsigned short* bptr = W1T + (size_t)(n0 + ar) * INP + aq * 8;

    int lane = t & 63, wave = t >> 6;
    int wm = (wave & 1) * 32, wn = (wave >> 1) * 32;
    int ml = lane & 15, quad = lane >> 4, q8 = quad * 8;

    f32x4 acc[2][2] = {};
    for (int k0 = 0; k0 < INP; k0 += 32) {
        float4 a0 = *(const float4*)(aptr + k0);
        float4 a1 = *(const float4*)(aptr + k0 + 4);
        uint4 bv = *(const uint4*)(bptr + k0);
        *(uint4*)&As[ar][aq * 8] = pack8(a0, a1);
        *(uint4*)&Bs[ar][aq * 8] = bv;
        __syncthreads();
        bf16x8 af[2], bfr[2];
#pragma unroll
        for (int mi = 0; mi < 2; ++mi) af[mi]  = *(const bf16x8*)&As[wm + mi * 16 + ml][q8];
#pragma unroll
        for (int ni = 0; ni < 2; ++ni) bfr[ni] = *(const bf16x8*)&Bs[wn + ni * 16 + ml][q8];
#pragma unroll
        for (int mi = 0; mi < 2; ++mi)
#pragma unroll
            for (int ni = 0; ni < 2; ++ni)
                acc[mi][ni] = __builtin_amdgcn_mfma_f32_16x16x32_bf16(af[mi], bfr[ni], acc[mi][ni], 0, 0, 0);
        __syncthreads();
    }
#pragma unroll
    for (int mi = 0; mi < 2; ++mi)
#pragma unroll
        for (int r = 0; r < 4; ++r) {
            int row = m0 + wm + mi * 16 + quad * 4 + r;
            float d2 = 1.0f / (dgz[row] + 1.0f);
#pragma unroll
            for (int ni = 0; ni < 2; ++ni) {
                int col = n0 + wn + ni * 16 + ml;
                float c = acc[mi][ni][r];
                xwz[(size_t)row * HID + col] = c;
                hbz[(size_t)row * HID + col] = d2 * c + b1[col];
            }
        }
}

// yw = BN(h) @ W2 ; out = yw/(deg+1) + b2   (BN affine fused into staging)
__global__ __launch_bounds__(256) void k_gemm2(
    const float* __restrict__ hbase, const float* __restrict__ rstdg,
    const float* __restrict__ shiftc, const unsigned short* __restrict__ W2T,
    const float* __restrict__ b2, const float* __restrict__ deg,
    float* __restrict__ yw, float* __restrict__ out) {
    __shared__ __align__(16) unsigned short As[64][40];
    __shared__ __align__(16) unsigned short Bs[64][40];
    int z = blockIdx.z;
    const float* hz = hbase + (size_t)z * BATCH * HID;
    const float* gz = rstdg + z * HID;
    const float* sz = shiftc + z * HID;
    const float* dgz = deg + z * BATCH;
    float* ywz = yw + (size_t)z * BATCH * OUTC;
    float* oz = out + (size_t)z * BATCH * OUTC;
    int m0 = blockIdx.y * 64, n0 = blockIdx.x * 64;
    int t = threadIdx.x;
    int ar = t >> 2, aq = t & 3;
    const float* aptr = hz + (size_t)(m0 + ar) * HID + aq * 8;
    const unsigned short* bptr = W2T + (size_t)(n0 + ar) * HID + aq * 8;

    int lane = t & 63, wave = t >> 6;
    int wm = (wave & 1) * 32, wn = (wave >> 1) * 32;
    int ml = lane & 15, quad = lane >> 4, q8 = quad * 8;

    f32x4 acc[2][2] = {};
    for (int k0 = 0; k0 < HID; k0 += 32) {
        float4 h0 = *(const float4*)(aptr + k0);
        float4 h1 = *(const float4*)(aptr + k0 + 4);
        float4 g0 = *(const float4*)(gz + k0 + aq * 8);
        float4 g1 = *(const float4*)(gz + k0 + aq * 8 + 4);
        float4 s0 = *(const float4*)(sz + k0 + aq * 8);
        float4 s1 = *(const float4*)(sz + k0 + aq * 8 + 4);
        float4 a0 = make_float4(h0.x * g0.x + s0.x, h0.y * g0.y + s0.y,
                                h0.z * g0.z + s0.z, h0.w * g0.w + s0.w);
        float4 a1 = make_float4(h1.x * g1.x + s1.x, h1.y * g1.y + s1.y,
                                h1.z * g1.z + s1.z, h1.w * g1.w + s1.w);
        uint4 bv = *(const uint4*)(bptr + k0);
        *(uint4*)&As[ar][aq * 8] = pack8(a0, a1);
        *(uint4*)&Bs[ar][aq * 8] = bv;
        __syncthreads();
        bf16x8 af[2], bfr[2];
#pragma unroll
        for (int mi = 0; mi < 2; ++mi) af[mi]  = *(const bf16x8*)&As[wm + mi * 16 + ml][q8];
#pragma unroll
        for (int ni = 0; ni < 2; ++ni) bfr[ni] = *(const bf16x8*)&Bs[wn + ni * 16 + ml][q8];
#pragma unroll
        for (int mi = 0; mi < 2; ++mi)
#pragma unroll
            for (int ni = 0; ni < 2; ++ni)
                acc[mi][ni] = __builtin_amdgcn_mfma_f32_16x16x32_bf16(af[mi], bfr[ni], acc[mi][ni], 0, 0, 0);
        __syncthreads();
    }
#pragma unroll
    for (int mi = 0; mi < 2; ++mi)
#pragma unroll
        for (int r = 0; r < 4; ++r) {
            int row = m0 + wm + mi * 16 + quad * 4 + r;
            float d2 = 1.0f / (dgz[row] + 1.0f);
#pragma unroll
            for (int ni = 0; ni < 2; ++ni) {
                int col = n0 + wn + ni * 16 + ml;
                float c = acc[mi][ni][r];
                ywz[(size_t)row * OUTC + col] = c;
                oz[(size_t)row * OUTC + col] = d2 * c + b2[col];
            }
        }
}

// ---------------- edge aggregation (scatter-add) ----------------
__global__ void k_agg(const int2* __restrict__ edges, const int* __restrict__ kcount,
                      const float* __restrict__ deg, const float* __restrict__ src_mat,
                      float* __restrict__ dst_mat, int ncol) {
    int z = blockIdx.z;
    int K = kcount[z];
    const int2* ed = edges + (size_t)z * ENUM;
    const float* dgz = deg + z * BATCH;
    const float* sm = src_mat + (size_t)z * BATCH * ncol;
    float* dm = dst_mat + (size_t)z * BATCH * ncol;
    for (int e = blockIdx.x; e < K; e += gridDim.x) {
        int2 E = ed[e];
        float w = rsqrtf(dgz[E.x] + 1.0f) * rsqrtf(dgz[E.y] + 1.0f);
        const float* srow = sm + (size_t)E.x * ncol;
        float* drow = dm + (size_t)E.y * ncol;
        for (int c = threadIdx.x; c < ncol; c += blockDim.x)
            atomicAdd(&drow[c], w * srow[c]);
    }
}

// ---------------- batch norm ----------------
__global__ __launch_bounds__(256) void k_bnstats(const float* __restrict__ hbase,
                                                 float* __restrict__ musum,
                                                 float* __restrict__ sqsum) {
    int z = blockIdx.z;
    const float* h = hbase + (size_t)z * BATCH * HID;
    int c0 = threadIdx.x;
    int r0 = blockIdx.x * 32;
    float s1a = 0, s2a = 0, s1b = 0, s2b = 0;
    for (int rr = 0; rr < 32; ++rr) {
        const float* row = h + (size_t)(r0 + rr) * HID;
        float va = row[c0];
        float vb = row[c0 + 256];
        s1a += va; s2a += va * va;
        s1b += vb; s2b += vb * vb;
    }
    atomicAdd(&musum[z * HID + c0], s1a);       atomicAdd(&sqsum[z * HID + c0], s2a);
    atomicAdd(&musum[z * HID + c0 + 256], s1b); atomicAdd(&sqsum[z * HID + c0 + 256], s2b);
}

__global__ void k_bnfinal(const float* __restrict__ musum, const float* __restrict__ sqsum,
                          const float* __restrict__ gamma, const float* __restrict__ beta,
                          float* __restrict__ rstdg, float* __restrict__ shiftc) {
    int z = blockIdx.x;
    int c = threadIdx.x;
    float mu = musum[z * HID + c] * (1.0f / BATCH);
    float ex2 = sqsum[z * HID + c] * (1.0f / BATCH);
    float var = ex2 - mu * mu;
    float g = rsqrtf(var + BN_EPS) * gamma[c];
    rstdg[z * HID + c] = g;
    shiftc[z * HID + c] = beta[c] - mu * g;
}

// ---------------- launch ----------------
extern "C" void kernel_launch(void* const* d_in, const int* in_sizes, int n_in,
                              void* d_out, int out_size, void* d_ws, size_t ws_size,
                              hipStream_t stream) {
    const float* features    = (const float*)d_in[0];
    const float* W1          = (const float*)d_in[1];
    const float* b1          = (const float*)d_in[2];
    const float* W2          = (const float*)d_in[3];
    const float* b2          = (const float*)d_in[4];
    const float* gamma       = (const float*)d_in[5];
    const float* beta        = (const float*)d_in[6];
    const int*   edge_index  = (const int*)d_in[7];
    const int*   batch_nodes = (const int*)d_in[8];
    float* out = (float*)d_out;

    char* p = (char*)d_ws;
    size_t cur = 0;
    auto alloc = [&](size_t bytes) {
        void* r = p + cur;
        cur = (cur + bytes + 255) & ~(size_t)255;
        return r;
    };
    int*   inv    = (int*)  alloc(NNODES * sizeof(int));
    int*   appear = (int*)  alloc(RNUM * BATCH * sizeof(int));
    int*   rankA  = (int*)  alloc(RNUM * BATCH * sizeof(int));
    int*   kcount = (int*)  alloc(RNUM * sizeof(int));
    float* deg    = (float*)alloc(RNUM * BATCH * sizeof(float));
    float* musum  = (float*)alloc(RNUM * HID * sizeof(float));
    float* sqsum  = (float*)alloc(RNUM * HID * sizeof(float));
    float* rstdg  = (float*)alloc(RNUM * HID * sizeof(float));
    float* shiftc = (float*)alloc(RNUM * HID * sizeof(float));
    unsigned short* W1T = (unsigned short*)alloc((size_t)HID * INP * sizeof(unsigned short));
    unsigned short* W2T = (unsigned short*)alloc((size_t)OUTC * HID * sizeof(unsigned short));
    int2*  edges  = (int2*) alloc((size_t)RNUM * ENUM * sizeof(int2));
    float* xw     = (float*)alloc((size_t)RNUM * BATCH * HID * sizeof(float));
    float* hbase  = (float*)alloc((size_t)RNUM * BATCH * HID * sizeof(float));
    float* yw     = (float*)alloc((size_t)RNUM * BATCH * OUTC * sizeof(float));
    (void)ws_size; (void)in_sizes; (void)n_in; (void)out_size;

    k_wt<<<dim3(16, 16, 2), 256, 0, stream>>>(W1, W2, W1T, W2T);
    k_init<<<(NNODES + 255) / 256, 256, 0, stream>>>(inv, appear, deg, musum, sqsum, kcount);
    k_scatter_inv<<<BATCH / 256, 256, 0, stream>>>(batch_nodes, inv);

    k_mask<<<dim3(512, 1, RNUM), 256, 0, stream>>>(edge_index, inv, appear, edges, kcount);
    k_scan2048<<<RNUM, 1024, 0, stream>>>(appear, rankA);
    k_deg<<<dim3(64, 1, RNUM), 256, 0, stream>>>(edges, rankA, kcount, deg);

    k_gemm1<<<dim3(HID / 64, BATCH / 64, RNUM), 256, 0, stream>>>(
        features, batch_nodes, W1T, b1, deg, xw, hbase);
    k_agg<<<dim3(256, 1, RNUM), 256, 0, stream>>>(edges, kcount, deg, xw, hbase, HID);

    k_bnstats<<<dim3(64, 1, RNUM), 256, 0, stream>>>(hbase, musum, sqsum);
    k_bnfinal<<<RNUM, HID, 0, stream>>>(musum, sqsum, gamma, beta, rstdg, shiftc);

    k_gemm2<<<dim3(OUTC / 64, BATCH / 64, RNUM), 256, 0, stream>>>(
        hbase, rstdg, shiftc, W2T, b2, deg, yw, out);
    k_agg<<<dim3(256, 1, RNUM), 256, 0, stream>>>(edges, kcount, deg, yw, out, OUTC);
}